// Round 23
// baseline (86.498 us; speedup 1.0000x reference)
//
#include <hip/hip_runtime.h>

typedef __attribute__((ext_vector_type(8))) short short8;
typedef __attribute__((ext_vector_type(4))) float f32x4;
typedef __attribute__((ext_vector_type(4))) ushort u16x4;

constexpr int NN = 10000;
constexpr int NE = 160000;
constexpr int NT = NE / 16;                    // 10000 edge-tiles
constexpr int TPSTR = 64;                      // tp row stride in USHORT (128 B = 2 lines)
constexpr int GBLK = 625;                      // gather blocks (625*16 = NN)
constexpr float EPSV = 1e-5f;
constexpr float INV3 = 0.57735026918962576f;   // 1/sqrt(3)
constexpr float ALPHA = 0.20412414523193152f;  // 1/sqrt(16+8)

__device__ __forceinline__ ushort f2bf(float x) {
  unsigned u = __float_as_uint(x);
  u += 0x7fffu + ((u >> 16) & 1u);
  return (ushort)(u >> 16);
}
__device__ __forceinline__ float bf2f(ushort u) {
  return __uint_as_float(((unsigned)u) << 16);
}
__device__ __forceinline__ f32x4 mfma16(short8 a, short8 b, f32x4 c) {
  return __builtin_amdgcn_mfma_f32_16x16x32_bf16(a, b, c, 0, 0, 0);
}
__device__ __forceinline__ void st4u(ushort* p, f32x4 v) {
  u16x4 o;
#pragma unroll
  for (int j = 0; j < 4; ++j) o[j] = f2bf(v[j]);
  *(u16x4*)p = o;
}

// ---------------- K0: W2 -> bf16 A-frags; zero deg; b2 |max| flag ----------------
constexpr int PREP_DEGB = (NN + 63) / 64;      // 157
__global__ __launch_bounds__(64) void prep_w2(const float* __restrict__ w2,
                                              short8* __restrict__ w2bf,
                                              int* __restrict__ deg,
                                              const float* __restrict__ b2,
                                              float* __restrict__ flag) {
  int b = blockIdx.x;
  int lane = threadIdx.x;
  if (b < 72) {                // 72 = 36 jt * 2 kc
    int jt = b >> 1, kc = b & 1;
    int g = lane >> 4, c = lane & 15;
    short8 v;
#pragma unroll
    for (int j = 0; j < 8; ++j)
      v[j] = (short)f2bf(w2[(kc * 32 + 8 * g + j) * 576 + jt * 16 + c]);
    w2bf[(jt * 2 + kc) * 64 + lane] = v;
  } else if (b < 72 + PREP_DEGB) {
    int idx = (b - 72) * 64 + lane;
    if (idx < NN) deg[idx] = 0;
  } else {                     // last block: flag = max|b2|
    float m = 0.f;
    for (int i = lane; i < 576; i += 64) m = fmaxf(m, fabsf(b2[i]));
#pragma unroll
    for (int off = 1; off < 64; off <<= 1) m = fmaxf(m, __shfl_xor(m, off));
    if (lane == 0) *flag = m;
  }
}

// ---------------- K2: FUSED mlp1+conv; CSR slot atomic hoisted to phase 0 ----------------
// r23: atomicAdd(&wcur[src],1) issued at tile top (independent of compute);
// ~500cy latency hides under the whole MFMA body. +1 live VGPR only.
constexpr int CSTR = 68;
constexpr unsigned SM_W2 = 4608 * 16;                       // 73728 B
constexpr unsigned SM_B2 = 576 * 4;                         // 2304 B
constexpr unsigned SM_W1 = 512 * 16;                        // 8192 B
constexpr unsigned SM_B1 = 64 * 4;                          // 256 B
constexpr unsigned SM_HL = 8 * 16 * 72 * 2;                 // 18432 B (transpose)
constexpr unsigned SM_SCR = 8 * 16 * CSTR * 4;              // 34816 B
constexpr unsigned SM_TOTAL = SM_W2 + SM_B2 + SM_W1 + SM_B1 + SM_HL + SM_SCR; // 137728

__global__ __launch_bounds__(512) void conv_kernel(
    const float* __restrict__ ef, const float* __restrict__ w1,
    const float* __restrict__ b1, const short8* __restrict__ w2bf,
    const float* __restrict__ b2, const float* __restrict__ nf,
    const float* __restrict__ sh, const int* __restrict__ ei,
    int* __restrict__ wcur, float* __restrict__ efout, int do_copy,
    ushort* __restrict__ tp, const float* __restrict__ flagp)
{
  extern __shared__ char smem[];
  short8* w2lds = (short8*)smem;
  float*  b2lds = (float*)(smem + SM_W2);
  short8* w1f   = (short8*)(smem + SM_W2 + SM_B2);
  float*  b1lds = (float*)(smem + SM_W2 + SM_B2 + SM_W1);
  ushort* hlall = (ushort*)(smem + SM_W2 + SM_B2 + SM_W1 + SM_B1);
  float*  scrall = (float*)(smem + SM_W2 + SM_B2 + SM_W1 + SM_B1 + SM_HL);

  const int tid = threadIdx.x;
  for (int i = tid; i < 4608; i += 512) w2lds[i] = w2bf[i];
  for (int i = tid; i < 576; i += 512) b2lds[i] = b2[i];
  {  // W1 -> bf16 B-frags, one per thread (512 frags)
    int tile = tid >> 6, l = tid & 63;
    int nt = tile >> 1, kc = tile & 1;
    int gg = l >> 4, cc = l & 15;
    short8 v;
#pragma unroll
    for (int j = 0; j < 8; ++j)
      v[j] = (short)f2bf(w1[(kc * 32 + 8 * gg + j) * 64 + nt * 16 + cc]);
    w1f[tid] = v;
  }
  if (tid < 64) b1lds[tid] = b1[tid];
  const bool nob2 = (*flagp == 0.f);   // uniform
  __syncthreads();

  const int lane = tid & 63, wid = tid >> 6;
  const int g = lane >> 4, c = lane & 15;
  const int gh = g >> 1;
  const int e = lane >> 2, part = lane & 3;
  float* scr = scrall + wid * (16 * CSTR);
  ushort* hl = hlall + wid * (16 * 72);

  for (int t = blockIdx.x * 8 + wid; t < NT; t += gridDim.x * 8) {
    // ---- phase 0: issue gather loads + CSR slot claim (latency hides below)
    const int ege = t * 16 + e;
    const float* __restrict__ src = nf + (size_t)ei[ege] * 40;
    const f32x4 sv = *(const f32x4*)(sh + (size_t)ege * 4);
    const f32x4 v0 = *(const f32x4*)(src + part * 4);
    const f32x4 v1 = *(const f32x4*)(src + 16 + part * 4);
    f32x4 v2 = {};
    if (part < 2) v2 = *(const f32x4*)(src + 32 + part * 4);
    int pos = 0;
    if (g == 0) pos = atomicAdd(&wcur[ei[NE + t * 16 + c]], 1);  // one lane/edge

    // ---- phase 1: MLP1 GEMM (lane c = edge of this tile)
    const long ebase = (long)t * 16;
    short8 af[2];
    const float* rowp = ef + (ebase + c) * 64;
#pragma unroll
    for (int kc = 0; kc < 2; ++kc) {
      const f32x4* p = (const f32x4*)(rowp + kc * 32 + 8 * g);
      f32x4 lo = p[0], hi = p[1];
      if (do_copy) {
        f32x4* q = (f32x4*)(efout + (ebase + c) * 64 + kc * 32 + 8 * g);
        q[0] = lo; q[1] = hi;
      }
      short8 v;
#pragma unroll
      for (int j = 0; j < 4; ++j) { v[j] = (short)f2bf(lo[j]); v[4 + j] = (short)f2bf(hi[j]); }
      af[kc] = v;
    }
    f32x4 hacc[4] = {};
#pragma unroll
    for (int nt = 0; nt < 4; ++nt)
#pragma unroll
      for (int kc = 0; kc < 2; ++kc)
        hacc[nt] = mfma16(af[kc], w1f[(nt * 2 + kc) * 64 + lane], hacc[nt]);

    // ---- phase 2: bias+relu, per-wave LDS transpose -> h0/h1 (in-wave ordered)
#pragma unroll
    for (int nt = 0; nt < 4; ++nt) {
      float bv = b1lds[nt * 16 + c];
#pragma unroll
      for (int q = 0; q < 4; ++q) {
        float h = fmaxf(hacc[nt][q] + bv, 0.f);
        hl[(4 * g + q) * 72 + nt * 16 + c] = f2bf(h);
      }
    }
    const short8 h0 = *(const short8*)&hl[c * 72 + 8 * g];
    const short8 h1 = *(const short8*)&hl[c * 72 + 32 + 8 * g];

    // ---- phase 3: coefficient table from phase-0 regs (4 lanes per edge)
    {
      float* ce = scr + e * CSTR;
      f32x4 a0;
#pragma unroll
      for (int q = 0; q < 4; ++q) a0[q] = sv[0] * v0[q];
      *(f32x4*)(ce + 4 * part) = a0;
      *(f32x4*)(ce + 24 + 4 * part) = v0;
      *(f32x4*)(ce + 40 + 4 * part) = v1;
      if (part < 2) *(f32x4*)(ce + 56 + 4 * part) = v2;
#pragma unroll
      for (int uu = 0; uu < 2; ++uu) {
        int u = 2 * part + uu;
        ce[16 + u] = INV3 * (ce[40 + 3 * u] * sv[1] + ce[41 + 3 * u] * sv[2] +
                             ce[42 + 3 * u] * sv[3]);
      }
    }
    const float* __restrict__ cc = scr + c * CSTR;

    // ---- phase 4: j-GEMM + lane-local tensor product
    f32x4 out0acc = {0.f, 0.f, 0.f, 0.f};
    f32x4 c0acc = {0.f, 0.f, 0.f, 0.f};
    f32x4 c1acc[3] = {};

    if (nob2) {  // FAST PATH: zero-init d, independent d0/d1 chains
#pragma unroll
      for (int j4 = 0; j4 < 4; ++j4) {         // w00: u=jt, cc[0..15] vectorized
        const f32x4 a4 = *(const f32x4*)&cc[j4 * 4];
#pragma unroll
        for (int jj = 0; jj < 4; ++jj) {
          const int jt = j4 * 4 + jj;
          f32x4 z = {0.f, 0.f, 0.f, 0.f};
          f32x4 d0 = mfma16(w2lds[(jt * 2 + 0) * 64 + lane], h0, z);
          f32x4 d1 = mfma16(w2lds[(jt * 2 + 1) * 64 + lane], h1, z);
          float a = a4[jj];
#pragma unroll
          for (int q = 0; q < 4; ++q) {
            out0acc[q] = fmaf(a, d0[q], out0acc[q]);
            out0acc[q] = fmaf(a, d1[q], out0acc[q]);
          }
        }
      }
#pragma unroll
      for (int j4 = 0; j4 < 2; ++j4) {         // w11: u=jt-16, cc[16..23] vectorized
        const f32x4 a4 = *(const f32x4*)&cc[16 + j4 * 4];
#pragma unroll
        for (int jj = 0; jj < 4; ++jj) {
          const int jt = 16 + j4 * 4 + jj;
          f32x4 z = {0.f, 0.f, 0.f, 0.f};
          f32x4 d0 = mfma16(w2lds[(jt * 2 + 0) * 64 + lane], h0, z);
          f32x4 d1 = mfma16(w2lds[(jt * 2 + 1) * 64 + lane], h1, z);
          float a = a4[jj];
#pragma unroll
          for (int q = 0; q < 4; ++q) {
            out0acc[q] = fmaf(a, d0[q], out0acc[q]);
            out0acc[q] = fmaf(a, d1[q], out0acc[q]);
          }
        }
      }
#pragma unroll
      for (int jt = 24; jt < 32; ++jt) {       // w01: u=2(jt-24)+gh
        f32x4 z = {0.f, 0.f, 0.f, 0.f};
        f32x4 d0 = mfma16(w2lds[(jt * 2 + 0) * 64 + lane], h0, z);
        f32x4 d1 = mfma16(w2lds[(jt * 2 + 1) * 64 + lane], h1, z);
        float a = cc[24 + 2 * (jt - 24) + gh];
#pragma unroll
        for (int q = 0; q < 4; ++q) {
          c0acc[q] = fmaf(a, d0[q], c0acc[q]);
          c0acc[q] = fmaf(a, d1[q], c0acc[q]);
        }
      }
#pragma unroll
      for (int jt = 32; jt < 36; ++jt) {       // w10: u=2(jt-32)+gh
        f32x4 z = {0.f, 0.f, 0.f, 0.f};
        f32x4 d0 = mfma16(w2lds[(jt * 2 + 0) * 64 + lane], h0, z);
        f32x4 d1 = mfma16(w2lds[(jt * 2 + 1) * 64 + lane], h1, z);
        const int ub = 40 + 3 * (2 * (jt - 32) + gh);
#pragma unroll
        for (int i = 0; i < 3; ++i) {
          float a = cc[ub + i];
#pragma unroll
          for (int q = 0; q < 4; ++q) {
            c1acc[i][q] = fmaf(a, d0[q], c1acc[i][q]);
            c1acc[i][q] = fmaf(a, d1[q], c1acc[i][q]);
          }
        }
      }
    } else {     // GENERAL PATH (b2 != 0): bias in C operand
#pragma unroll
      for (int jt = 0; jt < 16; ++jt) {
        f32x4 d = *(const f32x4*)&b2lds[jt * 16 + 4 * g];
        d = mfma16(w2lds[(jt * 2 + 0) * 64 + lane], h0, d);
        d = mfma16(w2lds[(jt * 2 + 1) * 64 + lane], h1, d);
        float a = cc[jt];
#pragma unroll
        for (int q = 0; q < 4; ++q) out0acc[q] = fmaf(a, d[q], out0acc[q]);
      }
#pragma unroll
      for (int jt = 16; jt < 24; ++jt) {
        f32x4 d = *(const f32x4*)&b2lds[jt * 16 + 4 * g];
        d = mfma16(w2lds[(jt * 2 + 0) * 64 + lane], h0, d);
        d = mfma16(w2lds[(jt * 2 + 1) * 64 + lane], h1, d);
        float a = cc[16 + (jt - 16)];
#pragma unroll
        for (int q = 0; q < 4; ++q) out0acc[q] = fmaf(a, d[q], out0acc[q]);
      }
#pragma unroll
      for (int jt = 24; jt < 32; ++jt) {
        f32x4 d = *(const f32x4*)&b2lds[jt * 16 + 4 * g];
        d = mfma16(w2lds[(jt * 2 + 0) * 64 + lane], h0, d);
        d = mfma16(w2lds[(jt * 2 + 1) * 64 + lane], h1, d);
        float a = cc[24 + 2 * (jt - 24) + gh];
#pragma unroll
        for (int q = 0; q < 4; ++q) c0acc[q] = fmaf(a, d[q], c0acc[q]);
      }
#pragma unroll
      for (int jt = 32; jt < 36; ++jt) {
        f32x4 d = *(const f32x4*)&b2lds[jt * 16 + 4 * g];
        d = mfma16(w2lds[(jt * 2 + 0) * 64 + lane], h0, d);
        d = mfma16(w2lds[(jt * 2 + 1) * 64 + lane], h1, d);
        const int ub = 40 + 3 * (2 * (jt - 32) + gh);
#pragma unroll
        for (int i = 0; i < 3; ++i) {
          float a = cc[ub + i];
#pragma unroll
          for (int q = 0; q < 4; ++q) c1acc[i][q] = fmaf(a, d[q], c1acc[i][q]);
        }
      }
    }

    // fold gh halves (lane ^ 32)
#pragma unroll
    for (int q = 0; q < 4; ++q) c0acc[q] += __shfl_xor(c0acc[q], 32);
#pragma unroll
    for (int i = 0; i < 3; ++i)
#pragma unroll
      for (int q = 0; q < 4; ++q) c1acc[i][q] += __shfl_xor(c1acc[i][q], 32);

    // ---- store into the slot claimed at phase 0
    const int eg = t * 16 + c;
    const f32x4 shv = *(const f32x4*)(sh + (size_t)eg * 4);
    pos = __shfl(pos, c);                                  // broadcast to all g
    ushort* tpr = tp + (size_t)pos * TPSTR;
    f32x4 o0;
#pragma unroll
    for (int q = 0; q < 4; ++q) o0[q] = ALPHA * out0acc[q];
    st4u(tpr + 4 * g, o0);
    if (g < 2) {
      float wv[12];
#pragma unroll
      for (int q = 0; q < 4; ++q)
#pragma unroll
        for (int i = 0; i < 3; ++i)
          wv[q * 3 + i] = ALPHA * (shv[1 + i] * c0acc[q] + shv[0] * c1acc[i][q]);
#pragma unroll
      for (int p = 0; p < 3; ++p) {
        f32x4 v = {wv[4 * p], wv[4 * p + 1], wv[4 * p + 2], wv[4 * p + 3]};
        st4u(tpr + 16 + 12 * g + 4 * p, v);
      }
    }
  }
}

// ---------------- CSR build ----------------
__global__ __launch_bounds__(256) void hist_kernel(const int* __restrict__ ei,
                                                   int* __restrict__ deg) {
  for (int e = blockIdx.x * 256 + threadIdx.x; e < NE; e += gridDim.x * 256)
    atomicAdd(&deg[ei[NE + e]], 1);
}

// wave-level shfl_up scan, 2 barriers total
__global__ __launch_bounds__(1024) void scan_kernel(const int* __restrict__ deg,
                                                    int* __restrict__ rowoff,
                                                    int* __restrict__ wcur) {
  __shared__ int wsum[16];
  const int t = threadIdx.x;
  const int lane = t & 63, wid = t >> 6;
  const int base = t * 10;
  int d[10];
  int sum = 0;
#pragma unroll
  for (int j = 0; j < 10; ++j) {
    int n = base + j;
    d[j] = (n < NN) ? deg[n] : 0;
    sum += d[j];
  }
  int val = sum;                       // inclusive scan within wave
#pragma unroll
  for (int off = 1; off < 64; off <<= 1) {
    int v = __shfl_up(val, off);
    if (lane >= off) val += v;
  }
  if (lane == 63) wsum[wid] = val;
  __syncthreads();
  if (t < 16) {
    int v = wsum[t];
#pragma unroll
    for (int off = 1; off < 16; off <<= 1) {
      int u = __shfl_up(v, off);
      if (t >= off) v += u;
    }
    wsum[t] = v;                       // inclusive over waves
  }
  __syncthreads();
  const int waveoff = (wid > 0) ? wsum[wid - 1] : 0;
  int run = waveoff + (val - sum);     // exclusive prefix for this thread
#pragma unroll
  for (int j = 0; j < 10; ++j) {
    int n = base + j;
    if (n < NN) { rowoff[n] = run; wcur[n] = run; }
    run += d[j];
  }
  if (t == 1023) rowoff[NN] = run;
}

// ---------------- gather: linear CSR bf16 rows; per-block pstats (non-atomic) ----------------
__global__ __launch_bounds__(256) void gather_kernel(
    const ushort* __restrict__ tp, const int* __restrict__ rowoff,
    const float* __restrict__ nf, float* __restrict__ pre,
    float* __restrict__ pstats)
{
  __shared__ float ls[40];
  const int tid = threadIdx.x;
  if (tid < 40) ls[tid] = 0.f;
  __syncthreads();
  const int wid = tid >> 6, lane = tid & 63;
  float sacc = 0.f, qacc = 0.f;
  if (lane < 40) {
#pragma unroll 1
    for (int i = 0; i < 4; ++i) {
      const int n = blockIdx.x * 16 + wid * 4 + i;   // GBLK*16 == NN exactly
      const int r0 = rowoff[n], r1 = rowoff[n + 1];
      float s0 = 0.f, s1 = 0.f, s2 = 0.f, s3 = 0.f,
            s4 = 0.f, s5 = 0.f, s6 = 0.f, s7 = 0.f;
      int k = r0;
      for (; k + 8 <= r1; k += 8) {
        s0 += bf2f(tp[(size_t)(k + 0) * TPSTR + lane]);
        s1 += bf2f(tp[(size_t)(k + 1) * TPSTR + lane]);
        s2 += bf2f(tp[(size_t)(k + 2) * TPSTR + lane]);
        s3 += bf2f(tp[(size_t)(k + 3) * TPSTR + lane]);
        s4 += bf2f(tp[(size_t)(k + 4) * TPSTR + lane]);
        s5 += bf2f(tp[(size_t)(k + 5) * TPSTR + lane]);
        s6 += bf2f(tp[(size_t)(k + 6) * TPSTR + lane]);
        s7 += bf2f(tp[(size_t)(k + 7) * TPSTR + lane]);
      }
      for (; k < r1; ++k) s0 += bf2f(tp[(size_t)k * TPSTR + lane]);
      float s = ((s0 + s1) + (s2 + s3)) + ((s4 + s5) + (s6 + s7));
      float val = s / fmaxf((float)(r1 - r0), 1.f) + nf[(size_t)n * 40 + lane];
      pre[(size_t)n * 40 + lane] = val;
      if (lane < 16) { sacc += val; qacc += val * val; }
      else qacc += val * val;
    }
    if (lane < 16) {
      atomicAdd(&ls[lane], sacc);
      atomicAdd(&ls[16 + lane], qacc);
    } else {
      atomicAdd(&ls[32 + (lane - 16) / 3], qacc);
    }
  }
  __syncthreads();
  if (tid < 40) pstats[(size_t)blockIdx.x * 40 + tid] = ls[tid];
}

// 40 blocks: channel c = blockIdx; sum 625 block-partials
__global__ __launch_bounds__(256) void stats_reduce(
    const float* __restrict__ pstats, float* __restrict__ stats)
{
  const int c = blockIdx.x;
  float s = 0.f;
  for (int i = threadIdx.x; i < GBLK; i += 256) s += pstats[(size_t)i * 40 + c];
#pragma unroll
  for (int off = 1; off < 64; off <<= 1) s += __shfl_xor(s, off);
  __shared__ float red[4];
  if ((threadIdx.x & 63) == 0) red[threadIdx.x >> 6] = s;
  __syncthreads();
  if (threadIdx.x == 0) stats[c] = (red[0] + red[1]) + (red[2] + red[3]);
}

__global__ __launch_bounds__(256) void node_pass2(
    const float* __restrict__ pre, const float* __restrict__ stats,
    const float* __restrict__ bnws, const float* __restrict__ bnbs,
    const float* __restrict__ bnwv, float* __restrict__ out)
{
  int idx = blockIdx.x * blockDim.x + threadIdx.x;
  if (idx >= NN * 40) return;
  int n = idx / 40;
  int c = idx - n * 40;
  float val = pre[idx];
  constexpr float invN = 1.0f / NN;
  if (c < 16) {
    float mu = stats[c] * invN;
    float var = stats[16 + c] * invN - mu * mu;
    out[idx] = (val - mu) * (rsqrtf(var + EPSV) * bnws[c]) + bnbs[c];
  } else {
    int u = (c - 16) / 3;
    float vn = stats[32 + u] * (invN / 3.0f);
    out[idx] = val * (rsqrtf(vn + EPSV) * bnwv[u]);
  }
}

__global__ __launch_bounds__(256) void copy_ef(const f32x4* __restrict__ src,
                                               f32x4* __restrict__ dst) {
  const int n4 = NE * 64 / 4;
  for (int i = blockIdx.x * blockDim.x + threadIdx.x; i < n4;
       i += gridDim.x * blockDim.x)
    dst[i] = src[i];
}

extern "C" void kernel_launch(void* const* d_in, const int* in_sizes, int n_in,
                              void* d_out, int out_size, void* d_ws, size_t ws_size,
                              hipStream_t stream) {
  (void)in_sizes; (void)n_in; (void)out_size;
  const float* nf   = (const float*)d_in[0];
  const float* ef   = (const float*)d_in[1];
  const float* sh   = (const float*)d_in[2];
  const int*   ei   = (const int*)d_in[3];
  const float* w1   = (const float*)d_in[4];
  const float* b1   = (const float*)d_in[5];
  const float* w2   = (const float*)d_in[6];
  const float* b2   = (const float*)d_in[7];
  const float* bnws = (const float*)d_in[8];
  const float* bnbs = (const float*)d_in[9];
  const float* bnwv = (const float*)d_in[10];

  float* out = (float*)d_out;
  float* efout = out + (size_t)NN * 40;

  // ws layout
  char* w = (char*)d_ws;
  int* deg     = (int*)w;                               // NN (zeroed by prep_w2)
  float* stats = (float*)(w + (size_t)NN * 4);          // 40; [44] = b2 flag
  float* flag  = stats + 44;
  int* rowoff  = (int*)(w + (size_t)NN * 4 + 192);      // NN+1
  int* wcur    = rowoff + NN + 1;
  float* pre   = (float*)(wcur + NN);                   // NN*40
  float* pstats = pre + (size_t)NN * 40;                // GBLK*40
  size_t base  = ((size_t)((char*)(pstats + (size_t)GBLK * 40) - w) + 255) & ~(size_t)255;
  short8* w2bf = (short8*)(w + base);                   // 73728 B
  size_t tpoff = (base + SM_W2 + 255) & ~(size_t)255;

  const size_t TPB = (size_t)NE * TPSTR * 2;            // 20.48 MB (bf16 rows)
  const size_t needA = tpoff + TPB;

  hipFuncSetAttribute((const void*)conv_kernel,
                      hipFuncAttributeMaxDynamicSharedMemorySize, SM_TOTAL);

  prep_w2<<<72 + PREP_DEGB + 1, 64, 0, stream>>>(w2, w2bf, deg, b2, flag);

  const int pblocks = (NN * 40 + 255) / 256;

  hist_kernel<<<625, 256, 0, stream>>>(ei, deg);
  scan_kernel<<<1, 1024, 0, stream>>>(deg, rowoff, wcur);

  if (ws_size >= needA) {            // Plan A: tp in ws; ef copy fused in conv
    ushort* tp = (ushort*)(w + tpoff);
    conv_kernel<<<256, 512, SM_TOTAL, stream>>>(
        ef, w1, b1, w2bf, b2, nf, sh, ei, wcur, efout, 1, tp, flag);
    gather_kernel<<<GBLK, 256, 0, stream>>>(tp, rowoff, nf, pre, pstats);
    stats_reduce<<<40, 256, 0, stream>>>(pstats, stats);
    node_pass2<<<pblocks, 256, 0, stream>>>(pre, stats, bnws, bnbs, bnwv, out);
  } else {                           // Plan D: tp in efout region; copy ef last
    ushort* tp = (ushort*)efout;                              // 20.48 MB <= 40.9 MB
    conv_kernel<<<256, 512, SM_TOTAL, stream>>>(
        ef, w1, b1, w2bf, b2, nf, sh, ei, wcur, efout, 0, tp, flag);
    gather_kernel<<<GBLK, 256, 0, stream>>>(tp, rowoff, nf, pre, pstats);
    stats_reduce<<<40, 256, 0, stream>>>(pstats, stats);
    node_pass2<<<pblocks, 256, 0, stream>>>(pre, stats, bnws, bnbs, bnwv, out);
    copy_ef<<<2048, 256, 0, stream>>>((const f32x4*)ef, (f32x4*)efout);
  }
}